// Round 13
// baseline (517.624 us; speedup 1.0000x reference)
//
#include <hip/hip_runtime.h>
#include <hip/hip_bf16.h>

#define H 128

typedef __attribute__((ext_vector_type(8))) _Float16 f16x8;
typedef __attribute__((ext_vector_type(4))) float f32x4;

static inline size_t align_up(size_t x, size_t a){ return (x + a - 1) & ~(a - 1); }

__device__ inline f32x4 mfma16h(f16x8 a, f16x8 b, f32x4 c){
  return __builtin_amdgcn_mfma_f32_16x16x32_f16(a, b, c, 0, 0, 0);
}

// async global->LDS, 16B per lane. LDS dest linear; swizzle via pre-swizzled global source.
__device__ inline void gload_lds16(const void* g, void* l){
  __builtin_amdgcn_global_load_lds(
      (const __attribute__((address_space(1))) void*)g,
      (__attribute__((address_space(3))) void*)l, 16, 0, 0);
}

// ---------------- weight pre-pack args: W[K][128] fp32 -> WT[128][K] f16 (single) ----------------
struct PackArgs {
  const float* src[10];
  _Float16* dst[10];
  int K[10];
  int start[11];
};

// ---------------- merged pack_w + bucket histograms (edges P/T + labels) ----------------
__global__ __launch_bounds__(256) void pack_hist(PackArgs pa, int nblk_pack,
    const int* __restrict__ src, const int* __restrict__ dst, int E,
    const int* __restrict__ lsrc, int EL,
    int* __restrict__ cnt_b_p, int* __restrict__ cnt_b_t, int* __restrict__ cnt_b_l, int histgrid){
  if ((int)blockIdx.x < nblk_pack){
    int t = blockIdx.x * 256 + threadIdx.x;
    if (t >= pa.start[10]) return;
    int m = 0;
    #pragma unroll
    for (int i = 1; i < 10; i++) if (t >= pa.start[i]) m = i;
    int local = t - pa.start[m];
    int k = local >> 7, n = local & 127;
    float w = pa.src[m][local];
    pa.dst[m][n * pa.K[m] + k] = (_Float16)w;
  } else {
    int bid = (int)blockIdx.x - nblk_pack;
    __shared__ int hp[256], ht[256], hl[256];
    int tid = threadIdx.x;
    hp[tid] = 0; ht[tid] = 0; hl[tid] = 0;
    __syncthreads();
    for (int i = bid * 256 + tid; i < E; i += histgrid * 256){
      atomicAdd(&hp[dst[i] >> 7], 1);
      atomicAdd(&ht[src[i] >> 9], 1);
    }
    for (int i = bid * 256 + tid; i < EL; i += histgrid * 256){
      atomicAdd(&hl[lsrc[i] >> 9], 1);
    }
    __syncthreads();
    if (hp[tid]) atomicAdd(&cnt_b_p[tid], hp[tid]);
    if (ht[tid]) atomicAdd(&cnt_b_t[tid], ht[tid]);
    if (hl[tid]) atomicAdd(&cnt_b_l[tid], hl[tid]);
  }
}

// ---------------- tiny scan of bucket counts -> bases + cursors (3 jobs) ----------------
__global__ void scan_buckets(const int* __restrict__ cb_p, const int* __restrict__ cb_t,
                             const int* __restrict__ cb_l, int nbp, int nbt, int nbl,
                             int* __restrict__ base_p, int* __restrict__ base_t, int* __restrict__ base_l,
                             int* __restrict__ cur_p, int* __restrict__ cur_t, int* __restrict__ cur_l){
  if (threadIdx.x == 0){
    int s = 0;
    for (int i = 0; i < nbp; i++){ base_p[i] = s; cur_p[i] = s; s += cb_p[i]; }
    base_p[nbp] = s;
  } else if (threadIdx.x == 1){
    int s = 0;
    for (int i = 0; i < nbt; i++){ base_t[i] = s; cur_t[i] = s; s += cb_t[i]; }
    base_t[nbt] = s;
  } else if (threadIdx.x == 2){
    int s = 0;
    for (int i = 0; i < nbl; i++){ base_l[i] = s; cur_l[i] = s; s += cb_l[i]; }
    base_l[nbl] = s;
  }
}

// ---------------- bin body (per-block LDS counting sort); vals==nullptr -> val = global index ----------------
__device__ inline void bin_body(const int* __restrict__ keys, const int* __restrict__ vals,
    int E, int shift, int nb, int* __restrict__ cursor, unsigned* __restrict__ rec_out, int chunk,
    int* hist, int* excl, int* gbase, unsigned* recs, unsigned char* binid){
  const int CH = 4096, IT = 16;
  int tid = threadIdx.x;
  int start = chunk * CH;
  int cnt = E - start; if (cnt > CH) cnt = CH;
  if (cnt <= 0) return;
  hist[tid] = 0;
  __syncthreads();
  int b[IT]; int rank[IT]; unsigned rc[IT];
  unsigned mask = (1u << shift) - 1u;
  #pragma unroll
  for (int q = 0; q < IT; q++){
    int i = tid + q * 256;
    if (i < cnt){
      int k = keys[start + i];
      int v = vals ? vals[start + i] : (start + i);
      b[q] = k >> shift;
      rc[q] = ((unsigned)v << shift) | ((unsigned)k & mask);
      rank[q] = atomicAdd(&hist[b[q]], 1);
    } else b[q] = -1;
  }
  __syncthreads();
  int lane = tid & 63, wid = tid >> 6;
  if (wid == 0){
    int h0 = hist[lane*4], h1 = hist[lane*4+1], h2 = hist[lane*4+2], h3 = hist[lane*4+3];
    int s = h0 + h1 + h2 + h3;
    int sc = s;
    #pragma unroll
    for (int o = 1; o < 64; o <<= 1){ int t = __shfl_up(sc, (unsigned)o, 64); if (lane >= o) sc += t; }
    int base = sc - s;
    excl[lane*4] = base; excl[lane*4+1] = base + h0;
    excl[lane*4+2] = base + h0 + h1; excl[lane*4+3] = base + h0 + h1 + h2;
  }
  __syncthreads();
  #pragma unroll
  for (int q = 0; q < IT; q++){
    if (b[q] >= 0){
      int pos = excl[b[q]] + rank[q];
      recs[pos] = rc[q];
      binid[pos] = (unsigned char)b[q];
    }
  }
  if (tid < nb && hist[tid] > 0) gbase[tid] = atomicAdd(&cursor[tid], hist[tid]);
  __syncthreads();
  for (int i = tid; i < cnt; i += 256){
    int bb = binid[i];
    rec_out[gbase[bb] + (i - excl[bb])] = recs[i];
  }
}

// merged bin: P edge chunks, T edge chunks, label chunks
__global__ __launch_bounds__(256) void bin3(const int* __restrict__ esrc, const int* __restrict__ edst,
    int E, int nb_p, int* cu_p, unsigned* rec_p, int nb_t, int* cu_t, unsigned* rec_t, int nchunks,
    const int* __restrict__ lsrc, int EL, int nb_l, int* cu_l, unsigned* rec_l, int nchunks_l){
  __shared__ int hist[256];
  __shared__ int excl[256];
  __shared__ int gbase[256];
  __shared__ unsigned recs[4096];
  __shared__ unsigned char binid[4096];
  if ((int)blockIdx.x < nchunks)
    bin_body(edst, esrc, E, 7, nb_p, cu_p, rec_p, blockIdx.x, hist, excl, gbase, recs, binid);
  else if ((int)blockIdx.x < 2 * nchunks)
    bin_body(esrc, edst, E, 9, nb_t, cu_t, rec_t, blockIdx.x - nchunks, hist, excl, gbase, recs, binid);
  else
    bin_body(lsrc, nullptr, EL, 9, nb_l, cu_l, rec_l, blockIdx.x - 2 * nchunks, hist, excl, gbase, recs, binid);
}

// ---------------- per-bucket CSR build body ----------------
template<int LOC, int LB>
__device__ inline void build_body(const unsigned* __restrict__ rec, const int* __restrict__ bbase,
    int nkeys, int E, int* __restrict__ off, float* __restrict__ inv, int* __restrict__ csr,
    int b, int nb, int* hist, int* excl, int* cur, int* wsum){
  int tid = threadIdx.x;
  int s = bbase[b], e = bbase[b + 1];
  for (int k = tid; k < LOC; k += 256){ hist[k] = 0; cur[k] = 0; }
  __syncthreads();
  for (int i = s + tid; i < e; i += 256) atomicAdd(&hist[rec[i] & (LOC - 1)], 1);
  __syncthreads();
  int lane = tid & 63, wid = tid >> 6;
  constexpr int BPT = (LOC + 255) / 256;
  int h[BPT]; int ssum = 0;
  #pragma unroll
  for (int q = 0; q < BPT; q++){
    int k = tid * BPT + q;
    h[q] = (k < LOC) ? hist[k] : 0;
    ssum += h[q];
  }
  int sc = ssum;
  #pragma unroll
  for (int o = 1; o < 64; o <<= 1){ int t = __shfl_up(sc, (unsigned)o, 64); if (lane >= o) sc += t; }
  if (lane == 63) wsum[wid] = sc;
  __syncthreads();
  int base = 0;
  for (int w = 0; w < wid; w++) base += wsum[w];
  int ex = base + sc - ssum;
  #pragma unroll
  for (int q = 0; q < BPT; q++){
    int k = tid * BPT + q;
    if (k < LOC) excl[k] = ex;
    ex += h[q];
  }
  __syncthreads();
  int keybase = b << LB;
  for (int k = tid; k < LOC; k += 256){
    int gk = keybase + k;
    if (gk < nkeys){
      off[gk] = s + excl[k];
      int c = hist[k];
      inv[gk] = 1.0f / (float)(c > 1 ? c : 1);
    }
  }
  if (b == nb - 1 && tid == 0) off[nkeys] = E;
  for (int i = s + tid; i < e; i += 256){
    unsigned r = rec[i];
    int k = (int)(r & (LOC - 1));
    int rk = atomicAdd(&cur[k], 1);
    csr[s + excl[k] + rk] = (int)(r >> LB);
  }
}

// merged build_csr: P buckets (LOC=128) then T buckets (LOC=512)
__global__ __launch_bounds__(256) void build2(
    const unsigned* rec_p, const int* bb_p, int NPk, int* off_p, float* inv_p, int* csr_p, int nb_p,
    const unsigned* rec_t, const int* bb_t, int NTk, int* off_t, float* inv_t, int* csr_t, int nb_t, int E){
  __shared__ int hist[512];
  __shared__ int excl[512];
  __shared__ int cur[512];
  __shared__ int wsum[8];
  if ((int)blockIdx.x < nb_p)
    build_body<128,7>(rec_p, bb_p, NPk, E, off_p, inv_p, csr_p, blockIdx.x, nb_p, hist, excl, cur, wsum);
  else
    build_body<512,9>(rec_t, bb_t, NTk, E, off_t, inv_t, csr_t, blockIdx.x - nb_p, nb_t, hist, excl, cur, wsum);
}

// ---------------- merged input projections (fp32 A -> f16 OUT), pipelined, single-f16 W ----------------
struct ProjJob {
  const float* A;
  const _Float16* WT;
  const float* bias;
  _Float16* OUT;
  int M;
  int ntiles;
  int nblk;
};
template<int KA>
__device__ inline void proj_body(ProjJob j, int bid, char* lds){
  constexpr int KST = KA / 32;
  constexpr int RB_A = KA * 4;
  constexpr int CHA = RB_A / 16;
  constexpr int NIA = 64 * CHA / 512;
  constexpr int ABYTES = 64 * RB_A;

  const int t    = threadIdx.x;
  const int wid  = t >> 6;
  const int lane = t & 63;
  const int l15  = lane & 15;
  const int lkg  = lane >> 4;
  const int colg = wid * 16 + l15;
  const int M = j.M, ntiles = j.ntiles, nblk = j.nblk;

  f16x8 wl[KST];
  {
    const _Float16* bh = j.WT + (size_t)colg * KA + lkg * 8;
    #pragma unroll
    for (int ks = 0; ks < KST; ks++) wl[ks] = *(const f16x8*)(bh + ks * 32);
  }
  const float bb = j.bias[colg];

  auto stage = [&](int tile, char* dstA){
    int row0 = tile * 64;
    #pragma unroll
    for (int q = 0; q < NIA; q++){
      int lc  = q * 512 + t;
      int row = lc / CHA;
      int ch  = lc - row * CHA;
      int grow = row0 + row; if (grow > M - 1) grow = M - 1;
      int gch = ch ^ (row & 7);
      gload_lds16((const char*)j.A + (size_t)grow * RB_A + gch * 16, dstA + lc * 16);
    }
  };

  int p = 0;
  if (bid < ntiles) stage(bid, lds);

  for (int t0 = bid; t0 < ntiles; t0 += nblk){
    const int row0 = t0 * 64;
    const int tn = t0 + nblk;
    const bool hasnext = tn < ntiles;
    if (hasnext) stage(tn, lds + (p ^ 1) * ABYTES);

    if (hasnext){
      if constexpr (NIA == 4) asm volatile("s_waitcnt vmcnt(4)" ::: "memory");
      else                    asm volatile("s_waitcnt vmcnt(2)" ::: "memory");
    } else {
      asm volatile("s_waitcnt vmcnt(0)" ::: "memory");
    }
    __builtin_amdgcn_s_barrier();
    asm volatile("" ::: "memory");

    const char* bufA = lds + p * ABYTES;

    f32x4 acc[4];
    #pragma unroll
    for (int tt = 0; tt < 4; tt++){
      acc[tt] = (f32x4){0.f, 0.f, 0.f, 0.f};
      const int rl = tt * 16 + l15;
      const int sw = rl & 7;
      const char* ap = bufA + rl * RB_A;
      #pragma unroll
      for (int ks = 0; ks < KST; ks++){
        int c0 = lkg * 2 + ks * 8;
        f32x4 a0 = *(const f32x4*)(ap + ((c0    ) ^ sw) * 16);
        f32x4 a1 = *(const f32x4*)(ap + ((c0 + 1) ^ sw) * 16);
        f16x8 af;
        #pragma unroll
        for (int e = 0; e < 8; e++) af[e] = (_Float16)(e < 4 ? a0[e] : a1[e - 4]);
        acc[tt] = mfma16h(af, wl[ks], acc[tt]);
      }
      acc[tt].x += bb; acc[tt].y += bb; acc[tt].z += bb; acc[tt].w += bb;
    }

    #pragma unroll
    for (int tt = 0; tt < 4; tt++){
      #pragma unroll
      for (int r = 0; r < 4; r++){
        int row = row0 + tt * 16 + lkg * 4 + r;
        if (row < M) j.OUT[(size_t)row * H + colg] = (_Float16)acc[tt][r];
      }
    }
    asm volatile("s_waitcnt lgkmcnt(0)" ::: "memory");
    __builtin_amdgcn_s_barrier();
    asm volatile("" ::: "memory");
    p ^= 1;
  }
}
__global__ __launch_bounds__(512) void proj2(ProjJob jt, ProjJob jp){
  __shared__ __align__(16) char lds[2 * 64 * 512];
  if ((int)blockIdx.x < jt.nblk) proj_body<128>(jt, blockIdx.x, lds);
  else                           proj_body<64>(jp, (int)blockIdx.x - jt.nblk, lds);
}

// ---------------- merged dual SAGE GEMM: two jobs (P and T), single-f16 W ----------------
struct SageJob {
  const _Float16* A;
  const _Float16* Bs;
  const _Float16* WlT;
  const _Float16* WrT;
  const float* bias;
  _Float16* OUT;
  int M;
  int ntiles;
  int nblk;
};
template<bool RELU>
__global__ __launch_bounds__(512, 8) void sage_mfma2(SageJob j0, SageJob j1){
  constexpr int KST = 4;
  constexpr int CHA = 16;
  constexpr int NIA = 2, NIB = 2;
  constexpr int ABYTES = 64 * 256;
  constexpr int BUFB = 2 * ABYTES;

  __shared__ __align__(16) char lds[2 * BUFB];
  __shared__ float red[8][64];

  const bool second = (int)blockIdx.x >= j0.nblk;
  const SageJob j = second ? j1 : j0;
  const int bid = (int)blockIdx.x - (second ? j0.nblk : 0);
  const int M = j.M, ntiles = j.ntiles, nblk = j.nblk;

  const int t    = threadIdx.x;
  const int wid  = t >> 6;
  const int lane = t & 63;
  const int l15  = lane & 15;
  const int lkg  = lane >> 4;
  const int colg = wid * 16 + l15;

  f16x8 wl[KST], wr[KST];
  {
    const _Float16* bh  = j.WlT + (size_t)colg * 128 + lkg * 8;
    const _Float16* bh2 = j.WrT + (size_t)colg * 128 + lkg * 8;
    #pragma unroll
    for (int ks = 0; ks < KST; ks++){
      wl[ks] = *(const f16x8*)(bh + ks * 32);
      wr[ks] = *(const f16x8*)(bh2 + ks * 32);
    }
  }
  const float bb = j.bias[colg];

  auto stage = [&](int tile, char* dstA, char* dstB){
    int row0 = tile * 64;
    #pragma unroll
    for (int q = 0; q < NIA; q++){
      int lc  = q * 512 + t;
      int row = lc / CHA;
      int ch  = lc - row * CHA;
      int grow = row0 + row; if (grow > M - 1) grow = M - 1;
      int gch = ch ^ (row & 7);
      gload_lds16((const char*)j.A + (size_t)grow * 256 + gch * 16, dstA + lc * 16);
    }
    #pragma unroll
    for (int q = 0; q < NIB; q++){
      int lc  = q * 512 + t;
      int row = lc >> 4;
      int ch  = lc & 15;
      int grow = row0 + row; if (grow > M - 1) grow = M - 1;
      int gch = ch ^ (row & 7);
      gload_lds16((const char*)j.Bs + (size_t)grow * 256 + gch * 16, dstB + lc * 16);
    }
  };

  int p = 0;
  if (bid < ntiles) stage(bid, lds, lds + ABYTES);

  for (int t0 = bid; t0 < ntiles; t0 += nblk){
    const int row0 = t0 * 64;
    const int tn = t0 + nblk;
    const bool hasnext = tn < ntiles;
    if (hasnext) stage(tn, lds + (p ^ 1) * BUFB, lds + (p ^ 1) * BUFB + ABYTES);

    if (hasnext) asm volatile("s_waitcnt vmcnt(4)" ::: "memory");
    else         asm volatile("s_waitcnt vmcnt(0)" ::: "memory");
    __builtin_amdgcn_s_barrier();
    asm volatile("" ::: "memory");

    const char* bufA = lds + p * BUFB;
    const char* bufB = bufA + ABYTES;

    f32x4 acc[4];
    #pragma unroll
    for (int tt = 0; tt < 4; tt++){
      acc[tt] = (f32x4){0.f, 0.f, 0.f, 0.f};
      const int rl = tt * 16 + l15;
      const int sw = rl & 7;
      const char* ap = bufA + rl * 256;
      #pragma unroll
      for (int ks = 0; ks < KST; ks++){
        f16x8 af = *(const f16x8*)(ap + ((ks * 4 + lkg) ^ sw) * 16);
        acc[tt] = mfma16h(af, wl[ks], acc[tt]);
      }
      const char* bp = bufB + rl * 256;
      #pragma unroll
      for (int ks = 0; ks < KST; ks++){
        f16x8 bf = *(const f16x8*)(bp + ((ks * 4 + lkg) ^ sw) * 16);
        acc[tt] = mfma16h(bf, wr[ks], acc[tt]);
      }
      acc[tt].x += bb; acc[tt].y += bb; acc[tt].z += bb; acc[tt].w += bb;
    }

    // l2norm
    #pragma unroll
    for (int tt = 0; tt < 4; tt++){
      #pragma unroll
      for (int r = 0; r < 4; r++){
        float v = acc[tt][r] * acc[tt][r];
        v += __shfl_xor(v, 1, 64);
        v += __shfl_xor(v, 2, 64);
        v += __shfl_xor(v, 4, 64);
        v += __shfl_xor(v, 8, 64);
        if (l15 == 0) red[wid][tt * 16 + lkg * 4 + r] = v;
      }
    }
    asm volatile("s_waitcnt lgkmcnt(0)" ::: "memory");
    __builtin_amdgcn_s_barrier();
    asm volatile("" ::: "memory");
    #pragma unroll
    for (int tt = 0; tt < 4; tt++){
      #pragma unroll
      for (int r = 0; r < 4; r++){
        int idx = tt * 16 + lkg * 4 + r;
        float s = 0.f;
        #pragma unroll
        for (int w2 = 0; w2 < 8; w2++) s += red[w2][idx];
        float scale = 1.f / fmaxf(sqrtf(s), 1e-12f);
        float v = acc[tt][r] * scale;
        if (RELU) v = fmaxf(v, 0.f);
        acc[tt][r] = v;
      }
    }
    #pragma unroll
    for (int tt = 0; tt < 4; tt++){
      #pragma unroll
      for (int r = 0; r < 4; r++){
        int row = row0 + tt * 16 + lkg * 4 + r;
        if (row < M) j.OUT[(size_t)row * H + colg] = (_Float16)acc[tt][r];
      }
    }
    p ^= 1;
  }
}

// ---------------- merged segment-mean: two gather jobs in one launch ----------------
struct AggJob {
  const _Float16* feat;
  const int* csr;
  const int* off;
  const float* inv;
  _Float16* out;
  int n;
  int nblk;   // blocks assigned to this job (16 rows/block)
};
__global__ __launch_bounds__(256) void agg2_kernel(AggJob j0, AggJob j1){
  const bool second = (int)blockIdx.x >= j0.nblk;
  const AggJob j = second ? j1 : j0;
  const int bid = (int)blockIdx.x - (second ? j0.nblk : 0);
  int g = bid * 16 + (threadIdx.x >> 4);
  int l = threadIdx.x & 15;
  if (g >= j.n) return;
  int s = j.off[g], e = j.off[g + 1];
  float c0[8], c1[8], c2[8], c3[8];
  #pragma unroll
  for (int q = 0; q < 8; q++){ c0[q] = 0.f; c1[q] = 0.f; c2[q] = 0.f; c3[q] = 0.f; }
  const _Float16* F = j.feat;
  int i = s;
  for (; i + 3 < e; i += 4){
    f16x8 v0 = *(const f16x8*)(F + (size_t)j.csr[i]     * H + l * 8);
    f16x8 v1 = *(const f16x8*)(F + (size_t)j.csr[i + 1] * H + l * 8);
    f16x8 v2 = *(const f16x8*)(F + (size_t)j.csr[i + 2] * H + l * 8);
    f16x8 v3 = *(const f16x8*)(F + (size_t)j.csr[i + 3] * H + l * 8);
    #pragma unroll
    for (int q = 0; q < 8; q++){
      c0[q] += (float)v0[q]; c1[q] += (float)v1[q];
      c2[q] += (float)v2[q]; c3[q] += (float)v3[q];
    }
  }
  for (; i < e; i++){
    f16x8 v0 = *(const f16x8*)(F + (size_t)j.csr[i] * H + l * 8);
    #pragma unroll
    for (int q = 0; q < 8; q++) c0[q] += (float)v0[q];
  }
  float iv = j.inv[g];
  f16x8 ov;
  #pragma unroll
  for (int q = 0; q < 8; q++){
    float r = (c0[q] + c1[q]) + (c2[q] + c3[q]);
    ov[q] = (_Float16)(r * iv);
  }
  *(f16x8*)(j.out + (size_t)g * H + l * 8) = ov;
}

// ---------------- link predictor: bucketed by lsrc>>9 for z_t locality ----------------
// rec = (pair_idx << 9) | (lsrc & 511); bucket b covers z_t rows [b*512, b*512+512).
__global__ __launch_bounds__(256) void dot_kernel(const _Float16* __restrict__ zt, const _Float16* __restrict__ zp,
                           const unsigned* __restrict__ rec_l, const int* __restrict__ base_l,
                           const int* __restrict__ ld, float* __restrict__ out, int CPB){
  int b = blockIdx.x / CPB;
  int c = blockIdx.x - b * CPB;
  int s = base_l[b], e = base_l[b + 1];
  int len = e - s;
  int cs = s + (int)(((long long)len * c) / CPB);
  int ce = s + (int)(((long long)len * (c + 1)) / CPB);
  int g = threadIdx.x >> 4;
  int l = threadIdx.x & 15;
  for (int i = cs + g; i < ce; i += 16){
    unsigned r = rec_l[i];
    int idx = (int)(r >> 9);
    int src = (b << 9) | (int)(r & 511u);
    int dst = ld[idx];
    f16x8 x = *(const f16x8*)&zt[(size_t)src * H + l * 8];
    f16x8 y = *(const f16x8*)&zp[(size_t)dst * H + l * 8];
    float v = 0.f;
    #pragma unroll
    for (int q = 0; q < 8; q++) v += (float)x[q] * (float)y[q];
    v += __shfl_xor(v, 1, 64);
    v += __shfl_xor(v, 2, 64);
    v += __shfl_xor(v, 4, 64);
    v += __shfl_xor(v, 8, 64);
    if (l == 0) out[idx] = v;
  }
}

extern "C" void kernel_launch(void* const* d_in, const int* in_sizes, int n_in,
                              void* d_out, int out_size, void* d_ws, size_t ws_size,
                              hipStream_t stream){
  const float* x_t  = (const float*)d_in[0];
  const float* x_p  = (const float*)d_in[1];
  const int*   esrc = (const int*)d_in[2];
  const int*   edst = (const int*)d_in[3];
  const int*   lsrc = (const int*)d_in[4];
  const int*   ldst = (const int*)d_in[5];
  const float* Wn_t = (const float*)d_in[6];
  const float* bn_t = (const float*)d_in[7];
  const float* Wn_p = (const float*)d_in[8];
  const float* bn_p = (const float*)d_in[9];
  const float* W1_l_p=(const float*)d_in[10]; const float* b1_p=(const float*)d_in[11]; const float* W1_r_p=(const float*)d_in[12];
  const float* W1_l_t=(const float*)d_in[13]; const float* b1_t=(const float*)d_in[14]; const float* W1_r_t=(const float*)d_in[15];
  const float* W2_l_p=(const float*)d_in[16]; const float* b2_p=(const float*)d_in[17]; const float* W2_r_p=(const float*)d_in[18];
  const float* W2_l_t=(const float*)d_in[19]; const float* b2_t=(const float*)d_in[20]; const float* W2_r_t=(const float*)d_in[21];
  float* out = (float*)d_out;

  const int FT = 128, FP = 64;
  int NT = in_sizes[0] / FT;
  int NP = in_sizes[1] / FP;
  int E  = in_sizes[2];
  int EL = in_sizes[4];

  const int SH_P = 7, SH_T = 9;
  int nb_p = (NP + (1 << SH_P) - 1) >> SH_P;
  int nb_t = (NT + (1 << SH_T) - 1) >> SH_T;
  int nb_l = (NT + 511) >> 9;   // label buckets over lsrc (track ids)

  char* base = (char*)d_ws;
  size_t o = 0;
  auto alloc = [&](size_t bytes) -> char* { char* p = base + o; o = align_up(o + bytes, 256); return p; };
  int*   cb_p  = (int*)alloc(256 * 4);
  int*   cb_t  = (int*)alloc(256 * 4);
  int*   cb_l  = (int*)alloc(256 * 4);
  size_t zero_bytes = o;
  int*   bb_p  = (int*)alloc(260 * 4);
  int*   bb_t  = (int*)alloc(260 * 4);
  int*   bb_l  = (int*)alloc(260 * 4);
  int*   cu_p  = (int*)alloc(256 * 4);
  int*   cu_t  = (int*)alloc(256 * 4);
  int*   cu_l  = (int*)alloc(256 * 4);
  int*   off_p = (int*)alloc((size_t)(NP + 1) * 4);
  int*   off_t = (int*)alloc((size_t)(NT + 1) * 4);
  float* inv_p = (float*)alloc((size_t)NP * 4);
  float* inv_t = (float*)alloc((size_t)NT * 4);
  unsigned* rec_p = (unsigned*)alloc((size_t)E * 4);
  unsigned* rec_t = (unsigned*)alloc((size_t)E * 4);
  unsigned* rec_l = (unsigned*)alloc((size_t)EL * 4);
  int*   csr_p = (int*)alloc((size_t)E * 4);
  int*   csr_t = (int*)alloc((size_t)E * 4);
  _Float16* h_t = (_Float16*)alloc((size_t)NT * H * 2);
  _Float16* h_p = (_Float16*)alloc((size_t)NP * H * 2);
  _Float16* a_t = (_Float16*)alloc((size_t)NT * H * 2);
  _Float16* a_p = (_Float16*)alloc((size_t)NP * H * 2);

  PackArgs pa;
  const float* wsrc[10] = {Wn_t, Wn_p, W1_l_p, W1_r_p, W1_l_t, W1_r_t, W2_l_p, W2_r_p, W2_l_t, W2_r_t};
  int Ks[10] = {128, 64, 128, 128, 128, 128, 128, 128, 128, 128};
  _Float16* wpk[10];
  int st = 0;
  for (int m = 0; m < 10; m++){
    wpk[m] = (_Float16*)alloc((size_t)128 * Ks[m] * 2);
    pa.src[m] = wsrc[m]; pa.dst[m] = wpk[m]; pa.K[m] = Ks[m]; pa.start[m] = st;
    st += Ks[m] * 128;
  }
  pa.start[10] = st;
  (void)ws_size; (void)n_in; (void)out_size;

  hipMemsetAsync(base, 0, zero_bytes, stream);

  // merged pack_w + bucket histograms (edges + labels)
  int nblk_pack = (st + 255) / 256;
  const int histgrid = 512;
  pack_hist<<<nblk_pack + histgrid, 256, 0, stream>>>(pa, nblk_pack, esrc, edst, E, lsrc, EL,
                                                      cb_p, cb_t, cb_l, histgrid);
  scan_buckets<<<1, 64, 0, stream>>>(cb_p, cb_t, cb_l, nb_p, nb_t, nb_l,
                                     bb_p, bb_t, bb_l, cu_p, cu_t, cu_l);
  int nchunks = (E + 4095) / 4096;
  int nchunks_l = (EL + 4095) / 4096;
  bin3<<<2 * nchunks + nchunks_l, 256, 0, stream>>>(esrc, edst, E, nb_p, cu_p, rec_p, nb_t, cu_t, rec_t, nchunks,
                                                    lsrc, EL, nb_l, cu_l, rec_l, nchunks_l);
  build2<<<nb_p + nb_t, 256, 0, stream>>>(rec_p, bb_p, NP, off_p, inv_p, csr_p, nb_p,
                                          rec_t, bb_t, NT, off_t, inv_t, csr_t, nb_t, E);

  // merged input projections
  int tiles_t = (NT + 63) / 64;
  int tiles_p = (NP + 63) / 64;
  int pblk_t = tiles_t < 448 ? tiles_t : 448;
  int pblk_p = tiles_p < 64 ? tiles_p : 64;
  ProjJob pjt{x_t, wpk[0], bn_t, h_t, NT, tiles_t, pblk_t};
  ProjJob pjp{x_p, wpk[1], bn_p, h_p, NP, tiles_p, pblk_p};
  proj2<<<pblk_t + pblk_p, 512, 0, stream>>>(pjt, pjp);

  // merged agg jobs: 16 rows per block
  int ablk_p = (NP + 15) / 16;
  int ablk_t = (NT + 15) / 16;
  AggJob aj_p1{h_t, csr_p, off_p, inv_p, a_p, NP, ablk_p};
  AggJob aj_t1{h_p, csr_t, off_t, inv_t, a_t, NT, ablk_t};
  AggJob aj_p2{a_t, csr_p, off_p, inv_p, h_p, NP, ablk_p};
  AggJob aj_t2{a_p, csr_t, off_t, inv_t, h_t, NT, ablk_t};

  // merged sage jobs
  int nblk_p = tiles_p < 96 ? tiles_p : 96;
  int nblk_t = tiles_t < 416 ? tiles_t : 416;
  SageJob sj1p{a_p, h_p, wpk[2], wpk[3], b1_p, a_p, NP, tiles_p, nblk_p};
  SageJob sj1t{a_t, h_t, wpk[4], wpk[5], b1_t, a_t, NT, tiles_t, nblk_t};
  SageJob sj2p{h_p, a_p, wpk[6], wpk[7], b2_p, h_p, NP, tiles_p, nblk_p};
  SageJob sj2t{h_t, a_t, wpk[8], wpk[9], b2_t, h_t, NT, tiles_t, nblk_t};

  // layer 1
  agg2_kernel<<<ablk_p + ablk_t, 256, 0, stream>>>(aj_p1, aj_t1);
  sage_mfma2<true><<<nblk_p + nblk_t, 512, 0, stream>>>(sj1p, sj1t);

  // layer 2
  agg2_kernel<<<ablk_p + ablk_t, 256, 0, stream>>>(aj_p2, aj_t2);
  sage_mfma2<false><<<nblk_p + nblk_t, 512, 0, stream>>>(sj2p, sj2t);

  // link prediction (bucketed)
  const int CPB = 10;
  dot_kernel<<<nb_l * CPB, 256, 0, stream>>>(h_t, h_p, rec_l, bb_l, ldst, out, CPB);
}

// Round 14
// 488.419 us; speedup vs baseline: 1.0598x; 1.0598x over previous
//
#include <hip/hip_runtime.h>
#include <hip/hip_bf16.h>

#define H 128

typedef __attribute__((ext_vector_type(8))) _Float16 f16x8;
typedef __attribute__((ext_vector_type(4))) float f32x4;

static inline size_t align_up(size_t x, size_t a){ return (x + a - 1) & ~(a - 1); }

__device__ inline f32x4 mfma16h(f16x8 a, f16x8 b, f32x4 c){
  return __builtin_amdgcn_mfma_f32_16x16x32_f16(a, b, c, 0, 0, 0);
}

// async global->LDS, 16B per lane. LDS dest linear; swizzle via pre-swizzled global source.
__device__ inline void gload_lds16(const void* g, void* l){
  __builtin_amdgcn_global_load_lds(
      (const __attribute__((address_space(1))) void*)g,
      (__attribute__((address_space(3))) void*)l, 16, 0, 0);
}

// ---------------- weight pre-pack args: W[K][128] fp32 -> WT[128][K] f16 (single) ----------------
struct PackArgs {
  const float* src[10];
  _Float16* dst[10];
  int K[10];
  int start[11];
};

// ---------------- input projection body (fp32 A -> f16 OUT), W fragments direct from fp32 ----------------
struct ProjJob {
  const float* A;
  const float* Wsrc;   // fp32 [KA][128]
  const float* bias;
  _Float16* OUT;
  int M;
  int ntiles;
  int nblk;
};
template<int KA>
__device__ inline void proj_body(ProjJob j, int bid, char* lds){
  constexpr int KST = KA / 32;
  constexpr int RB_A = KA * 4;
  constexpr int CHA = RB_A / 16;
  constexpr int NIA = 64 * CHA / 512;
  constexpr int ABYTES = 64 * RB_A;

  const int t    = threadIdx.x;
  const int wid  = t >> 6;
  const int lane = t & 63;
  const int l15  = lane & 15;
  const int lkg  = lane >> 4;
  const int colg = wid * 16 + l15;
  const int M = j.M, ntiles = j.ntiles, nblk = j.nblk;

  // W fragment: wl[ks][e] = (f16)Wsrc[(lkg*8 + ks*32 + e)*128 + colg]  (same rounding as pack_w)
  f16x8 wl[KST];
  #pragma unroll
  for (int ks = 0; ks < KST; ks++){
    #pragma unroll
    for (int e = 0; e < 8; e++)
      wl[ks][e] = (_Float16)j.Wsrc[(size_t)(lkg * 8 + ks * 32 + e) * 128 + colg];
  }
  const float bb = j.bias[colg];

  auto stage = [&](int tile, char* dstA){
    int row0 = tile * 64;
    #pragma unroll
    for (int q = 0; q < NIA; q++){
      int lc  = q * 512 + t;
      int row = lc / CHA;
      int ch  = lc - row * CHA;
      int grow = row0 + row; if (grow > M - 1) grow = M - 1;
      int gch = ch ^ (row & 7);
      gload_lds16((const char*)j.A + (size_t)grow * RB_A + gch * 16, dstA + lc * 16);
    }
  };

  int p = 0;
  if (bid < ntiles) stage(bid, lds);

  for (int t0 = bid; t0 < ntiles; t0 += nblk){
    const int row0 = t0 * 64;
    const int tn = t0 + nblk;
    const bool hasnext = tn < ntiles;
    if (hasnext) stage(tn, lds + (p ^ 1) * ABYTES);

    if (hasnext){
      if constexpr (NIA == 4) asm volatile("s_waitcnt vmcnt(4)" ::: "memory");
      else                    asm volatile("s_waitcnt vmcnt(2)" ::: "memory");
    } else {
      asm volatile("s_waitcnt vmcnt(0)" ::: "memory");
    }
    __builtin_amdgcn_s_barrier();
    asm volatile("" ::: "memory");

    const char* bufA = lds + p * ABYTES;

    f32x4 acc[4];
    #pragma unroll
    for (int tt = 0; tt < 4; tt++){
      acc[tt] = (f32x4){0.f, 0.f, 0.f, 0.f};
      const int rl = tt * 16 + l15;
      const int sw = rl & 7;
      const char* ap = bufA + rl * RB_A;
      #pragma unroll
      for (int ks = 0; ks < KST; ks++){
        int c0 = lkg * 2 + ks * 8;
        f32x4 a0 = *(const f32x4*)(ap + ((c0    ) ^ sw) * 16);
        f32x4 a1 = *(const f32x4*)(ap + ((c0 + 1) ^ sw) * 16);
        f16x8 af;
        #pragma unroll
        for (int e = 0; e < 8; e++) af[e] = (_Float16)(e < 4 ? a0[e] : a1[e - 4]);
        acc[tt] = mfma16h(af, wl[ks], acc[tt]);
      }
      acc[tt].x += bb; acc[tt].y += bb; acc[tt].z += bb; acc[tt].w += bb;
    }

    #pragma unroll
    for (int tt = 0; tt < 4; tt++){
      #pragma unroll
      for (int r = 0; r < 4; r++){
        int row = row0 + tt * 16 + lkg * 4 + r;
        if (row < M) j.OUT[(size_t)row * H + colg] = (_Float16)acc[tt][r];
      }
    }
    asm volatile("s_waitcnt lgkmcnt(0)" ::: "memory");
    __builtin_amdgcn_s_barrier();
    asm volatile("" ::: "memory");
    p ^= 1;
  }
}

// ---------------- mega1: pack_w + hist_buckets + proj_t + proj_p in ONE launch (all independent) ----------------
__global__ __launch_bounds__(512) void mega1(PackArgs pa, int nblk_pack,
    const int* __restrict__ esrc, const int* __restrict__ edst, int E,
    int* __restrict__ cnt_b_p, int* __restrict__ cnt_b_t, int histgrid,
    ProjJob jt, ProjJob jp){
  __shared__ __align__(16) char lds[2 * 64 * 512];
  int bid = (int)blockIdx.x;
  if (bid < nblk_pack){
    int t = bid * 512 + threadIdx.x;
    if (t >= pa.start[10]) return;
    int m = 0;
    #pragma unroll
    for (int i = 1; i < 10; i++) if (t >= pa.start[i]) m = i;
    int local = t - pa.start[m];
    int k = local >> 7, n = local & 127;
    pa.dst[m][n * pa.K[m] + k] = (_Float16)pa.src[m][local];
    return;
  }
  bid -= nblk_pack;
  if (bid < histgrid){
    int* hp = (int*)lds;
    int* ht = hp + 256;
    int tid = threadIdx.x;
    if (tid < 256){ hp[tid] = 0; ht[tid] = 0; }
    __syncthreads();
    for (int i = bid * 512 + tid; i < E; i += histgrid * 512){
      atomicAdd(&hp[edst[i] >> 7], 1);
      atomicAdd(&ht[esrc[i] >> 9], 1);
    }
    __syncthreads();
    if (tid < 256){
      if (hp[tid]) atomicAdd(&cnt_b_p[tid], hp[tid]);
      if (ht[tid]) atomicAdd(&cnt_b_t[tid], ht[tid]);
    }
    return;
  }
  bid -= histgrid;
  if (bid < jt.nblk) proj_body<128>(jt, bid, lds);
  else               proj_body<64>(jp, bid - jt.nblk, lds);
}

// ---------------- tiny scan of bucket counts -> bases + cursors ----------------
__global__ void scan_buckets(const int* __restrict__ cb_p, const int* __restrict__ cb_t, int nbp, int nbt,
                             int* __restrict__ base_p, int* __restrict__ base_t,
                             int* __restrict__ cur_p, int* __restrict__ cur_t){
  if (threadIdx.x == 0){
    int s = 0;
    for (int i = 0; i < nbp; i++){ base_p[i] = s; cur_p[i] = s; s += cb_p[i]; }
    base_p[nbp] = s;
  } else if (threadIdx.x == 1){
    int s = 0;
    for (int i = 0; i < nbt; i++){ base_t[i] = s; cur_t[i] = s; s += cb_t[i]; }
    base_t[nbt] = s;
  }
}

// ---------------- bin body (per-block LDS counting sort) ----------------
__device__ inline void bin_body(const int* __restrict__ keys, const int* __restrict__ vals,
    int E, int shift, int nb, int* __restrict__ cursor, unsigned* __restrict__ rec_out, int chunk,
    int* hist, int* excl, int* gbase, unsigned* recs, unsigned char* binid){
  const int CH = 4096, IT = 16;
  int tid = threadIdx.x;
  int start = chunk * CH;
  int cnt = E - start; if (cnt > CH) cnt = CH;
  if (cnt <= 0) return;
  hist[tid] = 0;
  __syncthreads();
  int b[IT]; int rank[IT]; unsigned rc[IT];
  unsigned mask = (1u << shift) - 1u;
  #pragma unroll
  for (int q = 0; q < IT; q++){
    int i = tid + q * 256;
    if (i < cnt){
      int k = keys[start + i], v = vals[start + i];
      b[q] = k >> shift;
      rc[q] = ((unsigned)v << shift) | ((unsigned)k & mask);
      rank[q] = atomicAdd(&hist[b[q]], 1);
    } else b[q] = -1;
  }
  __syncthreads();
  int lane = tid & 63, wid = tid >> 6;
  if (wid == 0){
    int h0 = hist[lane*4], h1 = hist[lane*4+1], h2 = hist[lane*4+2], h3 = hist[lane*4+3];
    int s = h0 + h1 + h2 + h3;
    int sc = s;
    #pragma unroll
    for (int o = 1; o < 64; o <<= 1){ int t = __shfl_up(sc, (unsigned)o, 64); if (lane >= o) sc += t; }
    int base = sc - s;
    excl[lane*4] = base; excl[lane*4+1] = base + h0;
    excl[lane*4+2] = base + h0 + h1; excl[lane*4+3] = base + h0 + h1 + h2;
  }
  __syncthreads();
  #pragma unroll
  for (int q = 0; q < IT; q++){
    if (b[q] >= 0){
      int pos = excl[b[q]] + rank[q];
      recs[pos] = rc[q];
      binid[pos] = (unsigned char)b[q];
    }
  }
  if (tid < nb && hist[tid] > 0) gbase[tid] = atomicAdd(&cursor[tid], hist[tid]);
  __syncthreads();
  for (int i = tid; i < cnt; i += 256){
    int bb = binid[i];
    rec_out[gbase[bb] + (i - excl[bb])] = recs[i];
  }
}

// merged bin_edges: P chunks then T chunks
__global__ __launch_bounds__(256) void bin2(const int* __restrict__ esrc, const int* __restrict__ edst,
    int E, int nb_p, int* cu_p, unsigned* rec_p, int nb_t, int* cu_t, unsigned* rec_t, int nchunks){
  __shared__ int hist[256];
  __shared__ int excl[256];
  __shared__ int gbase[256];
  __shared__ unsigned recs[4096];
  __shared__ unsigned char binid[4096];
  if ((int)blockIdx.x < nchunks)
    bin_body(edst, esrc, E, 7, nb_p, cu_p, rec_p, blockIdx.x, hist, excl, gbase, recs, binid);
  else
    bin_body(esrc, edst, E, 9, nb_t, cu_t, rec_t, blockIdx.x - nchunks, hist, excl, gbase, recs, binid);
}

// ---------------- per-bucket CSR build body ----------------
template<int LOC, int LB>
__device__ inline void build_body(const unsigned* __restrict__ rec, const int* __restrict__ bbase,
    int nkeys, int E, int* __restrict__ off, float* __restrict__ inv, int* __restrict__ csr,
    int b, int nb, int* hist, int* excl, int* cur, int* wsum){
  int tid = threadIdx.x;
  int s = bbase[b], e = bbase[b + 1];
  for (int k = tid; k < LOC; k += 256){ hist[k] = 0; cur[k] = 0; }
  __syncthreads();
  for (int i = s + tid; i < e; i += 256) atomicAdd(&hist[rec[i] & (LOC - 1)], 1);
  __syncthreads();
  int lane = tid & 63, wid = tid >> 6;
  constexpr int BPT = (LOC + 255) / 256;
  int h[BPT]; int ssum = 0;
  #pragma unroll
  for (int q = 0; q < BPT; q++){
    int k = tid * BPT + q;
    h[q] = (k < LOC) ? hist[k] : 0;
    ssum += h[q];
  }
  int sc = ssum;
  #pragma unroll
  for (int o = 1; o < 64; o <<= 1){ int t = __shfl_up(sc, (unsigned)o, 64); if (lane >= o) sc += t; }
  if (lane == 63) wsum[wid] = sc;
  __syncthreads();
  int base = 0;
  for (int w = 0; w < wid; w++) base += wsum[w];
  int ex = base + sc - ssum;
  #pragma unroll
  for (int q = 0; q < BPT; q++){
    int k = tid * BPT + q;
    if (k < LOC) excl[k] = ex;
    ex += h[q];
  }
  __syncthreads();
  int keybase = b << LB;
  for (int k = tid; k < LOC; k += 256){
    int gk = keybase + k;
    if (gk < nkeys){
      off[gk] = s + excl[k];
      int c = hist[k];
      inv[gk] = 1.0f / (float)(c > 1 ? c : 1);
    }
  }
  if (b == nb - 1 && tid == 0) off[nkeys] = E;
  for (int i = s + tid; i < e; i += 256){
    unsigned r = rec[i];
    int k = (int)(r & (LOC - 1));
    int rk = atomicAdd(&cur[k], 1);
    csr[s + excl[k] + rk] = (int)(r >> LB);
  }
}

// merged build_csr: P buckets (LOC=128) then T buckets (LOC=512)
__global__ __launch_bounds__(256) void build2(
    const unsigned* rec_p, const int* bb_p, int NPk, int* off_p, float* inv_p, int* csr_p, int nb_p,
    const unsigned* rec_t, const int* bb_t, int NTk, int* off_t, float* inv_t, int* csr_t, int nb_t, int E){
  __shared__ int hist[512];
  __shared__ int excl[512];
  __shared__ int cur[512];
  __shared__ int wsum[8];
  if ((int)blockIdx.x < nb_p)
    build_body<128,7>(rec_p, bb_p, NPk, E, off_p, inv_p, csr_p, blockIdx.x, nb_p, hist, excl, cur, wsum);
  else
    build_body<512,9>(rec_t, bb_t, NTk, E, off_t, inv_t, csr_t, blockIdx.x - nb_p, nb_t, hist, excl, cur, wsum);
}

// ---------------- merged dual SAGE GEMM: two jobs (P and T), single-f16 W ----------------
struct SageJob {
  const _Float16* A;
  const _Float16* Bs;
  const _Float16* WlT;
  const _Float16* WrT;
  const float* bias;
  _Float16* OUT;
  int M;
  int ntiles;
  int nblk;
};
template<bool RELU>
__global__ __launch_bounds__(512, 8) void sage_mfma2(SageJob j0, SageJob j1){
  constexpr int KST = 4;
  constexpr int CHA = 16;
  constexpr int NIA = 2, NIB = 2;
  constexpr int ABYTES = 64 * 256;
  constexpr int BUFB = 2 * ABYTES;

  __shared__ __align__(16) char lds[2 * BUFB];
  __shared__ float red[8][64];

  const bool second = (int)blockIdx.x >= j0.nblk;
  const SageJob j = second ? j1 : j0;
  const int bid = (int)blockIdx.x - (second ? j0.nblk : 0);
  const int M = j.M, ntiles = j.ntiles, nblk = j.nblk;

  const int t    = threadIdx.x;
  const int wid  = t >> 6;
  const int lane = t & 63;
  const int l15  = lane & 15;
  const int lkg  = lane >> 4;
  const int colg = wid * 16 + l15;

  f16x8 wl[KST], wr[KST];
  {
    const _Float16* bh  = j.WlT + (size_t)colg * 128 + lkg * 8;
    const _Float16* bh2 = j.WrT + (size_t)colg * 128 + lkg * 8;
    #pragma unroll
    for (int ks = 0; ks < KST; ks++){
      wl[ks] = *(const f16x8*)(bh + ks * 32);
      wr[ks] = *(const f16x8*)(bh2 + ks * 32);
    }
  }
  const float bb = j.bias[colg];

  auto stage = [&](int tile, char* dstA, char* dstB){
    int row0 = tile * 64;
    #pragma unroll
    for (int q = 0; q < NIA; q++){
      int lc  = q * 512 + t;
      int row = lc / CHA;
      int ch  = lc - row * CHA;
      int grow = row0 + row; if (grow > M - 1) grow = M - 1;
      int gch = ch ^ (row & 7);
      gload_lds16((const char*)j.A + (size_t)grow * 256 + gch * 16, dstA + lc * 16);
    }
    #pragma unroll
    for (int q = 0; q < NIB; q++){
      int lc  = q * 512 + t;
      int row = lc >> 4;
      int ch  = lc & 15;
      int grow = row0 + row; if (grow > M - 1) grow = M - 1;
      int gch = ch ^ (row & 7);
      gload_lds16((const char*)j.Bs + (size_t)grow * 256 + gch * 16, dstB + lc * 16);
    }
  };

  int p = 0;
  if (bid < ntiles) stage(bid, lds, lds + ABYTES);

  for (int t0 = bid; t0 < ntiles; t0 += nblk){
    const int row0 = t0 * 64;
    const int tn = t0 + nblk;
    const bool hasnext = tn < ntiles;
    if (hasnext) stage(tn, lds + (p ^ 1) * BUFB, lds + (p ^ 1) * BUFB + ABYTES);

    if (hasnext) asm volatile("s_waitcnt vmcnt(4)" ::: "memory");
    else         asm volatile("s_waitcnt vmcnt(0)" ::: "memory");
    __builtin_amdgcn_s_barrier();
    asm volatile("" ::: "memory");

    const char* bufA = lds + p * BUFB;
    const char* bufB = bufA + ABYTES;

    f32x4 acc[4];
    #pragma unroll
    for (int tt = 0; tt < 4; tt++){
      acc[tt] = (f32x4){0.f, 0.f, 0.f, 0.f};
      const int rl = tt * 16 + l15;
      const int sw = rl & 7;
      const char* ap = bufA + rl * 256;
      #pragma unroll
      for (int ks = 0; ks < KST; ks++){
        f16x8 af = *(const f16x8*)(ap + ((ks * 4 + lkg) ^ sw) * 16);
        acc[tt] = mfma16h(af, wl[ks], acc[tt]);
      }
      const char* bp = bufB + rl * 256;
      #pragma unroll
      for (int ks = 0; ks < KST; ks++){
        f16x8 bf = *(const f16x8*)(bp + ((ks * 4 + lkg) ^ sw) * 16);
        acc[tt] = mfma16h(bf, wr[ks], acc[tt]);
      }
      acc[tt].x += bb; acc[tt].y += bb; acc[tt].z += bb; acc[tt].w += bb;
    }

    // l2norm
    #pragma unroll
    for (int tt = 0; tt < 4; tt++){
      #pragma unroll
      for (int r = 0; r < 4; r++){
        float v = acc[tt][r] * acc[tt][r];
        v += __shfl_xor(v, 1, 64);
        v += __shfl_xor(v, 2, 64);
        v += __shfl_xor(v, 4, 64);
        v += __shfl_xor(v, 8, 64);
        if (l15 == 0) red[wid][tt * 16 + lkg * 4 + r] = v;
      }
    }
    asm volatile("s_waitcnt lgkmcnt(0)" ::: "memory");
    __builtin_amdgcn_s_barrier();
    asm volatile("" ::: "memory");
    #pragma unroll
    for (int tt = 0; tt < 4; tt++){
      #pragma unroll
      for (int r = 0; r < 4; r++){
        int idx = tt * 16 + lkg * 4 + r;
        float s = 0.f;
        #pragma unroll
        for (int w2 = 0; w2 < 8; w2++) s += red[w2][idx];
        float scale = 1.f / fmaxf(sqrtf(s), 1e-12f);
        float v = acc[tt][r] * scale;
        if (RELU) v = fmaxf(v, 0.f);
        acc[tt][r] = v;
      }
    }
    #pragma unroll
    for (int tt = 0; tt < 4; tt++){
      #pragma unroll
      for (int r = 0; r < 4; r++){
        int row = row0 + tt * 16 + lkg * 4 + r;
        if (row < M) j.OUT[(size_t)row * H + colg] = (_Float16)acc[tt][r];
      }
    }
    p ^= 1;
  }
}

// ---------------- merged segment-mean: two gather jobs in one launch ----------------
struct AggJob {
  const _Float16* feat;
  const int* csr;
  const int* off;
  const float* inv;
  _Float16* out;
  int n;
  int nblk;   // blocks assigned to this job (16 rows/block)
};
__global__ __launch_bounds__(256) void agg2_kernel(AggJob j0, AggJob j1){
  const bool second = (int)blockIdx.x >= j0.nblk;
  const AggJob j = second ? j1 : j0;
  const int bid = (int)blockIdx.x - (second ? j0.nblk : 0);
  int g = bid * 16 + (threadIdx.x >> 4);
  int l = threadIdx.x & 15;
  if (g >= j.n) return;
  int s = j.off[g], e = j.off[g + 1];
  float c0[8], c1[8], c2[8], c3[8];
  #pragma unroll
  for (int q = 0; q < 8; q++){ c0[q] = 0.f; c1[q] = 0.f; c2[q] = 0.f; c3[q] = 0.f; }
  const _Float16* F = j.feat;
  int i = s;
  for (; i + 3 < e; i += 4){
    f16x8 v0 = *(const f16x8*)(F + (size_t)j.csr[i]     * H + l * 8);
    f16x8 v1 = *(const f16x8*)(F + (size_t)j.csr[i + 1] * H + l * 8);
    f16x8 v2 = *(const f16x8*)(F + (size_t)j.csr[i + 2] * H + l * 8);
    f16x8 v3 = *(const f16x8*)(F + (size_t)j.csr[i + 3] * H + l * 8);
    #pragma unroll
    for (int q = 0; q < 8; q++){
      c0[q] += (float)v0[q]; c1[q] += (float)v1[q];
      c2[q] += (float)v2[q]; c3[q] += (float)v3[q];
    }
  }
  for (; i < e; i++){
    f16x8 v0 = *(const f16x8*)(F + (size_t)j.csr[i] * H + l * 8);
    #pragma unroll
    for (int q = 0; q < 8; q++) c0[q] += (float)v0[q];
  }
  float iv = j.inv[g];
  f16x8 ov;
  #pragma unroll
  for (int q = 0; q < 8; q++){
    float r = (c0[q] + c1[q]) + (c2[q] + c3[q]);
    ov[q] = (_Float16)(r * iv);
  }
  *(f16x8*)(j.out + (size_t)g * H + l * 8) = ov;
}

// ---------------- link predictor: 16-lane group per pair, 16B loads ----------------
__global__ __launch_bounds__(256) void dot_kernel(const _Float16* __restrict__ zt, const _Float16* __restrict__ zp,
                           const int* __restrict__ ls, const int* __restrict__ ld,
                           float* __restrict__ out, int n){
  int w = (blockIdx.x * 256 + threadIdx.x) >> 4;
  int l = threadIdx.x & 15;
  if (w >= n) return;
  f16x8 x = *(const f16x8*)&zt[(size_t)ls[w] * H + l * 8];
  f16x8 y = *(const f16x8*)&zp[(size_t)ld[w] * H + l * 8];
  float v = 0.f;
  #pragma unroll
  for (int q = 0; q < 8; q++) v += (float)x[q] * (float)y[q];
  v += __shfl_xor(v, 1, 64);
  v += __shfl_xor(v, 2, 64);
  v += __shfl_xor(v, 4, 64);
  v += __shfl_xor(v, 8, 64);
  if (l == 0) out[w] = v;
}

extern "C" void kernel_launch(void* const* d_in, const int* in_sizes, int n_in,
                              void* d_out, int out_size, void* d_ws, size_t ws_size,
                              hipStream_t stream){
  const float* x_t  = (const float*)d_in[0];
  const float* x_p  = (const float*)d_in[1];
  const int*   esrc = (const int*)d_in[2];
  const int*   edst = (const int*)d_in[3];
  const int*   lsrc = (const int*)d_in[4];
  const int*   ldst = (const int*)d_in[5];
  const float* Wn_t = (const float*)d_in[6];
  const float* bn_t = (const float*)d_in[7];
  const float* Wn_p = (const float*)d_in[8];
  const float* bn_p = (const float*)d_in[9];
  const float* W1_l_p=(const float*)d_in[10]; const float* b1_p=(const float*)d_in[11]; const float* W1_r_p=(const float*)d_in[12];
  const float* W1_l_t=(const float*)d_in[13]; const float* b1_t=(const float*)d_in[14]; const float* W1_r_t=(const float*)d_in[15];
  const float* W2_l_p=(const float*)d_in[16]; const float* b2_p=(const float*)d_in[17]; const float* W2_r_p=(const float*)d_in[18];
  const float* W2_l_t=(const float*)d_in[19]; const float* b2_t=(const float*)d_in[20]; const float* W2_r_t=(const float*)d_in[21];
  float* out = (float*)d_out;

  const int FT = 128, FP = 64;
  int NT = in_sizes[0] / FT;
  int NP = in_sizes[1] / FP;
  int E  = in_sizes[2];
  int EL = in_sizes[4];

  const int SH_P = 7, SH_T = 9;
  int nb_p = (NP + (1 << SH_P) - 1) >> SH_P;
  int nb_t = (NT + (1 << SH_T) - 1) >> SH_T;

  char* base = (char*)d_ws;
  size_t o = 0;
  auto alloc = [&](size_t bytes) -> char* { char* p = base + o; o = align_up(o + bytes, 256); return p; };
  int*   cb_p  = (int*)alloc(256 * 4);
  int*   cb_t  = (int*)alloc(256 * 4);
  size_t zero_bytes = o;
  int*   bb_p  = (int*)alloc(260 * 4);
  int*   bb_t  = (int*)alloc(260 * 4);
  int*   cu_p  = (int*)alloc(256 * 4);
  int*   cu_t  = (int*)alloc(256 * 4);
  int*   off_p = (int*)alloc((size_t)(NP + 1) * 4);
  int*   off_t = (int*)alloc((size_t)(NT + 1) * 4);
  float* inv_p = (float*)alloc((size_t)NP * 4);
  float* inv_t = (float*)alloc((size_t)NT * 4);
  unsigned* rec_p = (unsigned*)alloc((size_t)E * 4);
  unsigned* rec_t = (unsigned*)alloc((size_t)E * 4);
  int*   csr_p = (int*)alloc((size_t)E * 4);
  int*   csr_t = (int*)alloc((size_t)E * 4);
  _Float16* h_t = (_Float16*)alloc((size_t)NT * H * 2);
  _Float16* h_p = (_Float16*)alloc((size_t)NP * H * 2);
  _Float16* a_t = (_Float16*)alloc((size_t)NT * H * 2);
  _Float16* a_p = (_Float16*)alloc((size_t)NP * H * 2);

  PackArgs pa;
  const float* wsrc[10] = {Wn_t, Wn_p, W1_l_p, W1_r_p, W1_l_t, W1_r_t, W2_l_p, W2_r_p, W2_l_t, W2_r_t};
  int Ks[10] = {128, 64, 128, 128, 128, 128, 128, 128, 128, 128};
  _Float16* wpk[10];
  int st = 0;
  for (int m = 0; m < 10; m++){
    wpk[m] = (_Float16*)alloc((size_t)128 * Ks[m] * 2);
    pa.src[m] = wsrc[m]; pa.dst[m] = wpk[m]; pa.K[m] = Ks[m]; pa.start[m] = st;
    st += Ks[m] * 128;
  }
  pa.start[10] = st;
  (void)ws_size; (void)n_in; (void)out_size;

  hipMemsetAsync(base, 0, zero_bytes, stream);

  // mega1: pack_w + hist_buckets + both input projections (all independent)
  int tiles_t = (NT + 63) / 64;
  int tiles_p = (NP + 63) / 64;
  int pblk_t = tiles_t < 448 ? tiles_t : 448;
  int pblk_p = tiles_p < 64 ? tiles_p : 64;
  ProjJob pjt{x_t, Wn_t, bn_t, h_t, NT, tiles_t, pblk_t};
  ProjJob pjp{x_p, Wn_p, bn_p, h_p, NP, tiles_p, pblk_p};
  int nblk_pack = (st + 511) / 512;
  const int histgrid = 512;
  mega1<<<nblk_pack + histgrid + pblk_t + pblk_p, 512, 0, stream>>>(
      pa, nblk_pack, esrc, edst, E, cb_p, cb_t, histgrid, pjt, pjp);

  scan_buckets<<<1, 64, 0, stream>>>(cb_p, cb_t, nb_p, nb_t, bb_p, bb_t, cu_p, cu_t);
  int nchunks = (E + 4095) / 4096;
  bin2<<<2 * nchunks, 256, 0, stream>>>(esrc, edst, E, nb_p, cu_p, rec_p, nb_t, cu_t, rec_t, nchunks);
  build2<<<nb_p + nb_t, 256, 0, stream>>>(rec_p, bb_p, NP, off_p, inv_p, csr_p, nb_p,
                                          rec_t, bb_t, NT, off_t, inv_t, csr_t, nb_t, E);

  // merged agg jobs: 16 rows per block
  int ablk_p = (NP + 15) / 16;
  int ablk_t = (NT + 15) / 16;
  AggJob aj_p1{h_t, csr_p, off_p, inv_p, a_p, NP, ablk_p};
  AggJob aj_t1{h_p, csr_t, off_t, inv_t, a_t, NT, ablk_t};
  AggJob aj_p2{a_t, csr_p, off_p, inv_p, h_p, NP, ablk_p};
  AggJob aj_t2{a_p, csr_t, off_t, inv_t, h_t, NT, ablk_t};

  // merged sage jobs
  int nblk_p = tiles_p < 96 ? tiles_p : 96;
  int nblk_t = tiles_t < 416 ? tiles_t : 416;
  SageJob sj1p{a_p, h_p, wpk[2], wpk[3], b1_p, a_p, NP, tiles_p, nblk_p};
  SageJob sj1t{a_t, h_t, wpk[4], wpk[5], b1_t, a_t, NT, tiles_t, nblk_t};
  SageJob sj2p{h_p, a_p, wpk[6], wpk[7], b2_p, h_p, NP, tiles_p, nblk_p};
  SageJob sj2t{h_t, a_t, wpk[8], wpk[9], b2_t, h_t, NT, tiles_t, nblk_t};

  // layer 1
  agg2_kernel<<<ablk_p + ablk_t, 256, 0, stream>>>(aj_p1, aj_t1);
  sage_mfma2<true><<<nblk_p + nblk_t, 512, 0, stream>>>(sj1p, sj1t);

  // layer 2
  agg2_kernel<<<ablk_p + ablk_t, 256, 0, stream>>>(aj_p2, aj_t2);
  sage_mfma2<false><<<nblk_p + nblk_t, 512, 0, stream>>>(sj2p, sj2t);

  // link prediction
  dot_kernel<<<(EL + 15) / 16, 256, 0, stream>>>(h_t, h_p, lsrc, ldst, out, EL);
}

// Round 15
// 466.008 us; speedup vs baseline: 1.1108x; 1.0481x over previous
//
#include <hip/hip_runtime.h>
#include <hip/hip_bf16.h>

#define H 128

typedef __attribute__((ext_vector_type(8))) _Float16 f16x8;
typedef __attribute__((ext_vector_type(4))) float f32x4;

static inline size_t align_up(size_t x, size_t a){ return (x + a - 1) & ~(a - 1); }

__device__ inline f32x4 mfma16h(f16x8 a, f16x8 b, f32x4 c){
  return __builtin_amdgcn_mfma_f32_16x16x32_f16(a, b, c, 0, 0, 0);
}

// async global->LDS, 16B per lane. LDS dest linear; swizzle via pre-swizzled global source.
__device__ inline void gload_lds16(const void* g, void* l){
  __builtin_amdgcn_global_load_lds(
      (const __attribute__((address_space(1))) void*)g,
      (__attribute__((address_space(3))) void*)l, 16, 0, 0);
}

// in-block exclusive scan of 256 bucket counts (wave W does it); base_s in LDS
template<int W>
__device__ inline void scan256_wave(const int* __restrict__ cnt, int* base_s){
  int tid = threadIdx.x;
  if ((tid >> 6) == W){
    int lane = tid & 63;
    int v0 = cnt[lane*4], v1 = cnt[lane*4+1], v2 = cnt[lane*4+2], v3 = cnt[lane*4+3];
    int s = v0 + v1 + v2 + v3;
    int sc = s;
    #pragma unroll
    for (int o = 1; o < 64; o <<= 1){ int t = __shfl_up(sc, (unsigned)o, 64); if (lane >= o) sc += t; }
    int b = sc - s;
    base_s[lane*4] = b; base_s[lane*4+1] = b + v0;
    base_s[lane*4+2] = b + v0 + v1; base_s[lane*4+3] = b + v0 + v1 + v2;
  }
}

// ---------------- weight pre-pack args: W[K][128] fp32 -> WT[128][K] f16 (single) ----------------
struct PackArgs {
  const float* src[10];
  _Float16* dst[10];
  int K[10];
  int start[11];
};

// ---------------- input projection body (fp32 A -> f16 OUT), W fragments direct from fp32 ----------------
struct ProjJob {
  const float* A;
  const float* Wsrc;   // fp32 [KA][128]
  const float* bias;
  _Float16* OUT;
  int M;
  int ntiles;
  int nblk;
};
template<int KA>
__device__ inline void proj_body(ProjJob j, int bid, char* lds){
  constexpr int KST = KA / 32;
  constexpr int RB_A = KA * 4;
  constexpr int CHA = RB_A / 16;
  constexpr int NIA = 64 * CHA / 512;
  constexpr int ABYTES = 64 * RB_A;

  const int t    = threadIdx.x;
  const int wid  = t >> 6;
  const int lane = t & 63;
  const int l15  = lane & 15;
  const int lkg  = lane >> 4;
  const int colg = wid * 16 + l15;
  const int M = j.M, ntiles = j.ntiles, nblk = j.nblk;

  f16x8 wl[KST];
  #pragma unroll
  for (int ks = 0; ks < KST; ks++){
    #pragma unroll
    for (int e = 0; e < 8; e++)
      wl[ks][e] = (_Float16)j.Wsrc[(size_t)(lkg * 8 + ks * 32 + e) * 128 + colg];
  }
  const float bb = j.bias[colg];

  auto stage = [&](int tile, char* dstA){
    int row0 = tile * 64;
    #pragma unroll
    for (int q = 0; q < NIA; q++){
      int lc  = q * 512 + t;
      int row = lc / CHA;
      int ch  = lc - row * CHA;
      int grow = row0 + row; if (grow > M - 1) grow = M - 1;
      int gch = ch ^ (row & 7);
      gload_lds16((const char*)j.A + (size_t)grow * RB_A + gch * 16, dstA + lc * 16);
    }
  };

  int p = 0;
  if (bid < ntiles) stage(bid, lds);

  for (int t0 = bid; t0 < ntiles; t0 += nblk){
    const int row0 = t0 * 64;
    const int tn = t0 + nblk;
    const bool hasnext = tn < ntiles;
    if (hasnext) stage(tn, lds + (p ^ 1) * ABYTES);

    if (hasnext){
      if constexpr (NIA == 4) asm volatile("s_waitcnt vmcnt(4)" ::: "memory");
      else                    asm volatile("s_waitcnt vmcnt(2)" ::: "memory");
    } else {
      asm volatile("s_waitcnt vmcnt(0)" ::: "memory");
    }
    __builtin_amdgcn_s_barrier();
    asm volatile("" ::: "memory");

    const char* bufA = lds + p * ABYTES;

    f32x4 acc[4];
    #pragma unroll
    for (int tt = 0; tt < 4; tt++){
      acc[tt] = (f32x4){0.f, 0.f, 0.f, 0.f};
      const int rl = tt * 16 + l15;
      const int sw = rl & 7;
      const char* ap = bufA + rl * RB_A;
      #pragma unroll
      for (int ks = 0; ks < KST; ks++){
        int c0 = lkg * 2 + ks * 8;
        f32x4 a0 = *(const f32x4*)(ap + ((c0    ) ^ sw) * 16);
        f32x4 a1 = *(const f32x4*)(ap + ((c0 + 1) ^ sw) * 16);
        f16x8 af;
        #pragma unroll
        for (int e = 0; e < 8; e++) af[e] = (_Float16)(e < 4 ? a0[e] : a1[e - 4]);
        acc[tt] = mfma16h(af, wl[ks], acc[tt]);
      }
      acc[tt].x += bb; acc[tt].y += bb; acc[tt].z += bb; acc[tt].w += bb;
    }

    #pragma unroll
    for (int tt = 0; tt < 4; tt++){
      #pragma unroll
      for (int r = 0; r < 4; r++){
        int row = row0 + tt * 16 + lkg * 4 + r;
        if (row < M) j.OUT[(size_t)row * H + colg] = (_Float16)acc[tt][r];
      }
    }
    asm volatile("s_waitcnt lgkmcnt(0)" ::: "memory");
    __builtin_amdgcn_s_barrier();
    asm volatile("" ::: "memory");
    p ^= 1;
  }
}

// ---------------- mega1: pack_w + hist_buckets + proj_t + proj_p in ONE launch ----------------
__global__ __launch_bounds__(512) void mega1(PackArgs pa, int nblk_pack,
    const int* __restrict__ esrc, const int* __restrict__ edst, int E,
    int* __restrict__ cnt_b_p, int* __restrict__ cnt_b_t, int histgrid,
    ProjJob jt, ProjJob jp){
  __shared__ __align__(16) char lds[2 * 64 * 512];
  int bid = (int)blockIdx.x;
  if (bid < nblk_pack){
    int t = bid * 512 + threadIdx.x;
    if (t >= pa.start[10]) return;
    int m = 0;
    #pragma unroll
    for (int i = 1; i < 10; i++) if (t >= pa.start[i]) m = i;
    int local = t - pa.start[m];
    int k = local >> 7, n = local & 127;
    pa.dst[m][n * pa.K[m] + k] = (_Float16)pa.src[m][local];
    return;
  }
  bid -= nblk_pack;
  if (bid < histgrid){
    int* hp = (int*)lds;
    int* ht = hp + 256;
    int tid = threadIdx.x;
    if (tid < 256){ hp[tid] = 0; ht[tid] = 0; }
    __syncthreads();
    for (int i = bid * 512 + tid; i < E; i += histgrid * 512){
      atomicAdd(&hp[edst[i] >> 7], 1);
      atomicAdd(&ht[esrc[i] >> 9], 1);
    }
    __syncthreads();
    if (tid < 256){
      if (hp[tid]) atomicAdd(&cnt_b_p[tid], hp[tid]);
      if (ht[tid]) atomicAdd(&cnt_b_t[tid], ht[tid]);
    }
    return;
  }
  bid -= histgrid;
  if (bid < jt.nblk) proj_body<128>(jt, bid, lds);
  else               proj_body<64>(jp, bid - jt.nblk, lds);
}

// ---------------- bin body (per-block LDS counting sort); bases computed in-block from counts ----------------
__device__ inline void bin_body(const int* __restrict__ keys, const int* __restrict__ vals,
    int E, int shift, int nb, const int* __restrict__ cb, int* __restrict__ cur0,
    unsigned* __restrict__ rec_out, int chunk,
    int* hist, int* excl, int* base_s, int* gbase, unsigned* recs, unsigned char* binid){
  const int CH = 4096, IT = 16;
  int tid = threadIdx.x;
  int start = chunk * CH;
  int cnt = E - start; if (cnt > CH) cnt = CH;
  if (cnt <= 0) return;
  hist[tid] = 0;
  __syncthreads();
  int b[IT]; int rank[IT]; unsigned rc[IT];
  unsigned mask = (1u << shift) - 1u;
  #pragma unroll
  for (int q = 0; q < IT; q++){
    int i = tid + q * 256;
    if (i < cnt){
      int k = keys[start + i];
      int v = vals[start + i];
      b[q] = k >> shift;
      rc[q] = ((unsigned)v << shift) | ((unsigned)k & mask);
      rank[q] = atomicAdd(&hist[b[q]], 1);
    } else b[q] = -1;
  }
  __syncthreads();
  int lane = tid & 63, wid = tid >> 6;
  if (wid == 0){
    int h0 = hist[lane*4], h1 = hist[lane*4+1], h2 = hist[lane*4+2], h3 = hist[lane*4+3];
    int s = h0 + h1 + h2 + h3;
    int sc = s;
    #pragma unroll
    for (int o = 1; o < 64; o <<= 1){ int t = __shfl_up(sc, (unsigned)o, 64); if (lane >= o) sc += t; }
    int base = sc - s;
    excl[lane*4] = base; excl[lane*4+1] = base + h0;
    excl[lane*4+2] = base + h0 + h1; excl[lane*4+3] = base + h0 + h1 + h2;
  }
  scan256_wave<1>(cb, base_s);   // global bucket bases, computed redundantly per block
  __syncthreads();
  #pragma unroll
  for (int q = 0; q < IT; q++){
    if (b[q] >= 0){
      int pos = excl[b[q]] + rank[q];
      recs[pos] = rc[q];
      binid[pos] = (unsigned char)b[q];
    }
  }
  if (tid < nb && hist[tid] > 0) gbase[tid] = base_s[tid] + atomicAdd(&cur0[tid], hist[tid]);
  __syncthreads();
  for (int i = tid; i < cnt; i += 256){
    int bb = binid[i];
    rec_out[gbase[bb] + (i - excl[bb])] = recs[i];
  }
}

// merged bin_edges: P chunks then T chunks
__global__ __launch_bounds__(256) void bin2(const int* __restrict__ esrc, const int* __restrict__ edst,
    int E, int nb_p, const int* cb_p, int* cu_p, unsigned* rec_p,
    int nb_t, const int* cb_t, int* cu_t, unsigned* rec_t, int nchunks){
  __shared__ int hist[256];
  __shared__ int excl[256];
  __shared__ int base_s[256];
  __shared__ int gbase[256];
  __shared__ unsigned recs[4096];
  __shared__ unsigned char binid[4096];
  if ((int)blockIdx.x < nchunks)
    bin_body(edst, esrc, E, 7, nb_p, cb_p, cu_p, rec_p, blockIdx.x, hist, excl, base_s, gbase, recs, binid);
  else
    bin_body(esrc, edst, E, 9, nb_t, cb_t, cu_t, rec_t, blockIdx.x - nchunks, hist, excl, base_s, gbase, recs, binid);
}

// ---------------- per-bucket CSR build body; bucket range from in-block scan of counts ----------------
template<int LOC, int LB>
__device__ inline void build_body(const unsigned* __restrict__ rec, const int* __restrict__ cb,
    int nkeys, int E, int* __restrict__ off, float* __restrict__ inv, int* __restrict__ csr,
    int b, int nb, int* hist, int* excl, int* cur, int* base_s, int* wsum){
  int tid = threadIdx.x;
  scan256_wave<0>(cb, base_s);
  __syncthreads();
  int s = base_s[b], e = s + cb[b];
  for (int k = tid; k < LOC; k += 256){ hist[k] = 0; cur[k] = 0; }
  __syncthreads();
  for (int i = s + tid; i < e; i += 256) atomicAdd(&hist[rec[i] & (LOC - 1)], 1);
  __syncthreads();
  int lane = tid & 63, wid = tid >> 6;
  constexpr int BPT = (LOC + 255) / 256;
  int h[BPT]; int ssum = 0;
  #pragma unroll
  for (int q = 0; q < BPT; q++){
    int k = tid * BPT + q;
    h[q] = (k < LOC) ? hist[k] : 0;
    ssum += h[q];
  }
  int sc = ssum;
  #pragma unroll
  for (int o = 1; o < 64; o <<= 1){ int t = __shfl_up(sc, (unsigned)o, 64); if (lane >= o) sc += t; }
  if (lane == 63) wsum[wid] = sc;
  __syncthreads();
  int base = 0;
  for (int w = 0; w < wid; w++) base += wsum[w];
  int ex = base + sc - ssum;
  #pragma unroll
  for (int q = 0; q < BPT; q++){
    int k = tid * BPT + q;
    if (k < LOC) excl[k] = ex;
    ex += h[q];
  }
  __syncthreads();
  int keybase = b << LB;
  for (int k = tid; k < LOC; k += 256){
    int gk = keybase + k;
    if (gk < nkeys){
      off[gk] = s + excl[k];
      int c = hist[k];
      inv[gk] = 1.0f / (float)(c > 1 ? c : 1);
    }
  }
  if (b == nb - 1 && tid == 0) off[nkeys] = E;
  for (int i = s + tid; i < e; i += 256){
    unsigned r = rec[i];
    int k = (int)(r & (LOC - 1));
    int rk = atomicAdd(&cur[k], 1);
    csr[s + excl[k] + rk] = (int)(r >> LB);
  }
}

// merged build_csr: P buckets (LOC=128) then T buckets (LOC=512)
__global__ __launch_bounds__(256) void build2(
    const unsigned* rec_p, const int* cb_p, int NPk, int* off_p, float* inv_p, int* csr_p, int nb_p,
    const unsigned* rec_t, const int* cb_t, int NTk, int* off_t, float* inv_t, int* csr_t, int nb_t, int E){
  __shared__ int hist[512];
  __shared__ int excl[512];
  __shared__ int cur[512];
  __shared__ int base_s[256];
  __shared__ int wsum[8];
  if ((int)blockIdx.x < nb_p)
    build_body<128,7>(rec_p, cb_p, NPk, E, off_p, inv_p, csr_p, blockIdx.x, nb_p, hist, excl, cur, base_s, wsum);
  else
    build_body<512,9>(rec_t, cb_t, NTk, E, off_t, inv_t, csr_t, blockIdx.x - nb_p, nb_t, hist, excl, cur, base_s, wsum);
}

// ---------------- merged dual SAGE GEMM: two jobs (P and T), single-f16 W ----------------
struct SageJob {
  const _Float16* A;
  const _Float16* Bs;
  const _Float16* WlT;
  const _Float16* WrT;
  const float* bias;
  _Float16* OUT;
  int M;
  int ntiles;
  int nblk;
};
template<bool RELU>
__global__ __launch_bounds__(512, 8) void sage_mfma2(SageJob j0, SageJob j1){
  constexpr int KST = 4;
  constexpr int CHA = 16;
  constexpr int NIA = 2, NIB = 2;
  constexpr int ABYTES = 64 * 256;
  constexpr int BUFB = 2 * ABYTES;

  __shared__ __align__(16) char lds[2 * BUFB];
  __shared__ float red[8][64];

  const bool second = (int)blockIdx.x >= j0.nblk;
  const SageJob j = second ? j1 : j0;
  const int bid = (int)blockIdx.x - (second ? j0.nblk : 0);
  const int M = j.M, ntiles = j.ntiles, nblk = j.nblk;

  const int t    = threadIdx.x;
  const int wid  = t >> 6;
  const int lane = t & 63;
  const int l15  = lane & 15;
  const int lkg  = lane >> 4;
  const int colg = wid * 16 + l15;

  f16x8 wl[KST], wr[KST];
  {
    const _Float16* bh  = j.WlT + (size_t)colg * 128 + lkg * 8;
    const _Float16* bh2 = j.WrT + (size_t)colg * 128 + lkg * 8;
    #pragma unroll
    for (int ks = 0; ks < KST; ks++){
      wl[ks] = *(const f16x8*)(bh + ks * 32);
      wr[ks] = *(const f16x8*)(bh2 + ks * 32);
    }
  }
  const float bb = j.bias[colg];

  auto stage = [&](int tile, char* dstA, char* dstB){
    int row0 = tile * 64;
    #pragma unroll
    for (int q = 0; q < NIA; q++){
      int lc  = q * 512 + t;
      int row = lc / CHA;
      int ch  = lc - row * CHA;
      int grow = row0 + row; if (grow > M - 1) grow = M - 1;
      int gch = ch ^ (row & 7);
      gload_lds16((const char*)j.A + (size_t)grow * 256 + gch * 16, dstA + lc * 16);
    }
    #pragma unroll
    for (int q = 0; q < NIB; q++){
      int lc  = q * 512 + t;
      int row = lc >> 4;
      int ch  = lc & 15;
      int grow = row0 + row; if (grow > M - 1) grow = M - 1;
      int gch = ch ^ (row & 7);
      gload_lds16((const char*)j.Bs + (size_t)grow * 256 + gch * 16, dstB + lc * 16);
    }
  };

  int p = 0;
  if (bid < ntiles) stage(bid, lds, lds + ABYTES);

  for (int t0 = bid; t0 < ntiles; t0 += nblk){
    const int row0 = t0 * 64;
    const int tn = t0 + nblk;
    const bool hasnext = tn < ntiles;
    if (hasnext) stage(tn, lds + (p ^ 1) * BUFB, lds + (p ^ 1) * BUFB + ABYTES);

    if (hasnext) asm volatile("s_waitcnt vmcnt(4)" ::: "memory");
    else         asm volatile("s_waitcnt vmcnt(0)" ::: "memory");
    __builtin_amdgcn_s_barrier();
    asm volatile("" ::: "memory");

    const char* bufA = lds + p * BUFB;
    const char* bufB = bufA + ABYTES;

    f32x4 acc[4];
    #pragma unroll
    for (int tt = 0; tt < 4; tt++){
      acc[tt] = (f32x4){0.f, 0.f, 0.f, 0.f};
      const int rl = tt * 16 + l15;
      const int sw = rl & 7;
      const char* ap = bufA + rl * 256;
      #pragma unroll
      for (int ks = 0; ks < KST; ks++){
        f16x8 af = *(const f16x8*)(ap + ((ks * 4 + lkg) ^ sw) * 16);
        acc[tt] = mfma16h(af, wl[ks], acc[tt]);
      }
      const char* bp = bufB + rl * 256;
      #pragma unroll
      for (int ks = 0; ks < KST; ks++){
        f16x8 bf = *(const f16x8*)(bp + ((ks * 4 + lkg) ^ sw) * 16);
        acc[tt] = mfma16h(bf, wr[ks], acc[tt]);
      }
      acc[tt].x += bb; acc[tt].y += bb; acc[tt].z += bb; acc[tt].w += bb;
    }

    // l2norm
    #pragma unroll
    for (int tt = 0; tt < 4; tt++){
      #pragma unroll
      for (int r = 0; r < 4; r++){
        float v = acc[tt][r] * acc[tt][r];
        v += __shfl_xor(v, 1, 64);
        v += __shfl_xor(v, 2, 64);
        v += __shfl_xor(v, 4, 64);
        v += __shfl_xor(v, 8, 64);
        if (l15 == 0) red[wid][tt * 16 + lkg * 4 + r] = v;
      }
    }
    asm volatile("s_waitcnt lgkmcnt(0)" ::: "memory");
    __builtin_amdgcn_s_barrier();
    asm volatile("" ::: "memory");
    #pragma unroll
    for (int tt = 0; tt < 4; tt++){
      #pragma unroll
      for (int r = 0; r < 4; r++){
        int idx = tt * 16 + lkg * 4 + r;
        float s = 0.f;
        #pragma unroll
        for (int w2 = 0; w2 < 8; w2++) s += red[w2][idx];
        float scale = 1.f / fmaxf(sqrtf(s), 1e-12f);
        float v = acc[tt][r] * scale;
        if (RELU) v = fmaxf(v, 0.f);
        acc[tt][r] = v;
      }
    }
    #pragma unroll
    for (int tt = 0; tt < 4; tt++){
      #pragma unroll
      for (int r = 0; r < 4; r++){
        int row = row0 + tt * 16 + lkg * 4 + r;
        if (row < M) j.OUT[(size_t)row * H + colg] = (_Float16)acc[tt][r];
      }
    }
    p ^= 1;
  }
}

// ---------------- merged segment-mean: two gather jobs in one launch ----------------
struct AggJob {
  const _Float16* feat;
  const int* csr;
  const int* off;
  const float* inv;
  _Float16* out;
  int n;
  int nblk;   // blocks assigned to this job (16 rows/block)
};
__global__ __launch_bounds__(256) void agg2_kernel(AggJob j0, AggJob j1){
  const bool second = (int)blockIdx.x >= j0.nblk;
  const AggJob j = second ? j1 : j0;
  const int bid = (int)blockIdx.x - (second ? j0.nblk : 0);
  int g = bid * 16 + (threadIdx.x >> 4);
  int l = threadIdx.x & 15;
  if (g >= j.n) return;
  int s = j.off[g], e = j.off[g + 1];
  float c0[8], c1[8], c2[8], c3[8];
  #pragma unroll
  for (int q = 0; q < 8; q++){ c0[q] = 0.f; c1[q] = 0.f; c2[q] = 0.f; c3[q] = 0.f; }
  const _Float16* F = j.feat;
  int i = s;
  for (; i + 3 < e; i += 4){
    f16x8 v0 = *(const f16x8*)(F + (size_t)j.csr[i]     * H + l * 8);
    f16x8 v1 = *(const f16x8*)(F + (size_t)j.csr[i + 1] * H + l * 8);
    f16x8 v2 = *(const f16x8*)(F + (size_t)j.csr[i + 2] * H + l * 8);
    f16x8 v3 = *(const f16x8*)(F + (size_t)j.csr[i + 3] * H + l * 8);
    #pragma unroll
    for (int q = 0; q < 8; q++){
      c0[q] += (float)v0[q]; c1[q] += (float)v1[q];
      c2[q] += (float)v2[q]; c3[q] += (float)v3[q];
    }
  }
  for (; i < e; i++){
    f16x8 v0 = *(const f16x8*)(F + (size_t)j.csr[i] * H + l * 8);
    #pragma unroll
    for (int q = 0; q < 8; q++) c0[q] += (float)v0[q];
  }
  float iv = j.inv[g];
  f16x8 ov;
  #pragma unroll
  for (int q = 0; q < 8; q++){
    float r = (c0[q] + c1[q]) + (c2[q] + c3[q]);
    ov[q] = (_Float16)(r * iv);
  }
  *(f16x8*)(j.out + (size_t)g * H + l * 8) = ov;
}

// ---------------- link predictor: 16-lane group handles pairs g and g+G (4 loads in flight) ----------------
__global__ __launch_bounds__(256) void dot_kernel(const _Float16* __restrict__ zt, const _Float16* __restrict__ zp,
                           const int* __restrict__ ls, const int* __restrict__ ld,
                           float* __restrict__ out, int n, int G){
  int g = (blockIdx.x * 256 + threadIdx.x) >> 4;
  int l = threadIdx.x & 15;
  int w0 = g, w1 = g + G;
  bool h0 = w0 < n, h1 = w1 < n;
  f16x8 x0 = {}, y0 = {}, x1 = {}, y1 = {};
  if (h0){
    x0 = *(const f16x8*)&zt[(size_t)ls[w0] * H + l * 8];
    y0 = *(const f16x8*)&zp[(size_t)ld[w0] * H + l * 8];
  }
  if (h1){
    x1 = *(const f16x8*)&zt[(size_t)ls[w1] * H + l * 8];
    y1 = *(const f16x8*)&zp[(size_t)ld[w1] * H + l * 8];
  }
  float v0 = 0.f, v1 = 0.f;
  #pragma unroll
  for (int q = 0; q < 8; q++){ v0 += (float)x0[q] * (float)y0[q]; v1 += (float)x1[q] * (float)y1[q]; }
  #pragma unroll
  for (int o = 1; o <= 8; o <<= 1){
    v0 += __shfl_xor(v0, o, 64);
    v1 += __shfl_xor(v1, o, 64);
  }
  if (l == 0){
    if (h0) out[w0] = v0;
    if (h1) out[w1] = v1;
  }
}

extern "C" void kernel_launch(void* const* d_in, const int* in_sizes, int n_in,
                              void* d_out, int out_size, void* d_ws, size_t ws_size,
                              hipStream_t stream){
  const float* x_t  = (const float*)d_in[0];
  const float* x_p  = (const float*)d_in[1];
  const int*   esrc = (const int*)d_in[2];
  const int*   edst = (const int*)d_in[3];
  const int*   lsrc = (const int*)d_in[4];
  const int*   ldst = (const int*)d_in[5];
  const float* Wn_t = (const float*)d_in[6];
  const float* bn_t = (const float*)d_in[7];
  const float* Wn_p = (const float*)d_in[8];
  const float* bn_p = (const float*)d_in[9];
  const float* W1_l_p=(const float*)d_in[10]; const float* b1_p=(const float*)d_in[11]; const float* W1_r_p=(const float*)d_in[12];
  const float* W1_l_t=(const float*)d_in[13]; const float* b1_t=(const float*)d_in[14]; const float* W1_r_t=(const float*)d_in[15];
  const float* W2_l_p=(const float*)d_in[16]; const float* b2_p=(const float*)d_in[17]; const float* W2_r_p=(const float*)d_in[18];
  const float* W2_l_t=(const float*)d_in[19]; const float* b2_t=(const float*)d_in[20]; const float* W2_r_t=(const float*)d_in[21];
  float* out = (float*)d_out;

  const int FT = 128, FP = 64;
  int NT = in_sizes[0] / FT;
  int NP = in_sizes[1] / FP;
  int E  = in_sizes[2];
  int EL = in_sizes[4];

  const int SH_P = 7, SH_T = 9;
  int nb_p = (NP + (1 << SH_P) - 1) >> SH_P;
  int nb_t = (NT + (1 << SH_T) - 1) >> SH_T;

  char* base = (char*)d_ws;
  size_t o = 0;
  auto alloc = [&](size_t bytes) -> char* { char* p = base + o; o = align_up(o + bytes, 256); return p; };
  int*   cb_p  = (int*)alloc(256 * 4);
  int*   cb_t  = (int*)alloc(256 * 4);
  int*   cu_p  = (int*)alloc(256 * 4);
  int*   cu_t  = (int*)alloc(256 * 4);
  size_t zero_bytes = o;
  int*   off_p = (int*)alloc((size_t)(NP + 1) * 4);
  int*   off_t = (int*)alloc((size_t)(NT + 1) * 4);
  float* inv_p = (float*)alloc((size_t)NP * 4);
  float* inv_t = (float*)alloc((size_t)NT * 4);
  unsigned* rec_p = (unsigned*)alloc((size_t)E * 4);
  unsigned* rec_t = (unsigned*)alloc((size_t)E * 4);
  int*   csr_p = (int*)alloc((size_t)E * 4);
  int*   csr_t = (int*)alloc((size_t)E * 4);
  _Float16* h_t = (_Float16*)alloc((size_t)NT * H * 2);
  _Float16* h_p = (_Float16*)alloc((size_t)NP * H * 2);
  _Float16* a_t = (_Float16*)alloc((size_t)NT * H * 2);
  _Float16* a_p = (_Float16*)alloc((size_t)NP * H * 2);

  PackArgs pa;
  const float* wsrc[10] = {Wn_t, Wn_p, W1_l_p, W1_r_p, W1_l_t, W1_r_t, W2_l_p, W2_r_p, W2_l_t, W2_r_t};
  int Ks[10] = {128, 64, 128, 128, 128, 128, 128, 128, 128, 128};
  _Float16* wpk[10];
  int st = 0;
  for (int m = 0; m < 10; m++){
    wpk[m] = (_Float16*)alloc((size_t)128 * Ks[m] * 2);
    pa.src[m] = wsrc[m]; pa.dst[m] = wpk[m]; pa.K[m] = Ks[m]; pa.start[m] = st;
    st += Ks[m] * 128;
  }
  pa.start[10] = st;
  (void)ws_size; (void)n_in; (void)out_size;

  hipMemsetAsync(base, 0, zero_bytes, stream);

  // mega1: pack_w + hist_buckets + both input projections (all independent)
  int tiles_t = (NT + 63) / 64;
  int tiles_p = (NP + 63) / 64;
  int pblk_t = tiles_t < 448 ? tiles_t : 448;
  int pblk_p = tiles_p < 64 ? tiles_p : 64;
  ProjJob pjt{x_t, Wn_t, bn_t, h_t, NT, tiles_t, pblk_t};
  ProjJob pjp{x_p, Wn_p, bn_p, h_p, NP, tiles_p, pblk_p};
  int nblk_pack = (st + 511) / 512;
  const int histgrid = 512;
  mega1<<<nblk_pack + histgrid + pblk_t + pblk_p, 512, 0, stream>>>(
      pa, nblk_pack, esrc, edst, E, cb_p, cb_t, histgrid, pjt, pjp);

  int nchunks = (E + 4095) / 4096;
  bin2<<<2 * nchunks, 256, 0, stream>>>(esrc, edst, E, nb_p, cb_p, cu_p, rec_p,
                                        nb_t, cb_t, cu_t, rec_t, nchunks);
  build2<<<nb_p + nb_t, 256, 0, stream>>>(rec_p, cb_p, NP, off_p, inv_p, csr_p, nb_p,
                                          rec_t, cb_t, NT, off_t, inv_t, csr_t, nb_t, E);

  // merged agg jobs: 16 rows per block
  int ablk_p = (NP + 15) / 16;
  int ablk_t = (NT + 15) / 16;
  AggJob aj_p1{h_t, csr_p, off_p, inv_p, a_p, NP, ablk_p};
  AggJob aj_t1{h_p, csr_t, off_t, inv_t, a_t, NT, ablk_t};
  AggJob aj_p2{a_t, csr_p, off_p, inv_p, h_p, NP, ablk_p};
  AggJob aj_t2{a_p, csr_t, off_t, inv_t, h_t, NT, ablk_t};

  // merged sage jobs
  int nblk_p = tiles_p < 96 ? tiles_p : 96;
  int nblk_t = tiles_t < 416 ? tiles_t : 416;
  SageJob sj1p{a_p, h_p, wpk[2], wpk[3], b1_p, a_p, NP, tiles_p, nblk_p};
  SageJob sj1t{a_t, h_t, wpk[4], wpk[5], b1_t, a_t, NT, tiles_t, nblk_t};
  SageJob sj2p{h_p, a_p, wpk[6], wpk[7], b2_p, h_p, NP, tiles_p, nblk_p};
  SageJob sj2t{h_t, a_t, wpk[8], wpk[9], b2_t, h_t, NT, tiles_t, nblk_t};

  // layer 1
  agg2_kernel<<<ablk_p + ablk_t, 256, 0, stream>>>(aj_p1, aj_t1);
  sage_mfma2<true><<<nblk_p + nblk_t, 512, 0, stream>>>(sj1p, sj1t);

  // layer 2
  agg2_kernel<<<ablk_p + ablk_t, 256, 0, stream>>>(aj_p2, aj_t2);
  sage_mfma2<false><<<nblk_p + nblk_t, 512, 0, stream>>>(sj2p, sj2t);

  // link prediction: 2 pairs per 16-lane group
  int nhalf = (EL + 1) / 2;
  int dblk = (nhalf + 15) / 16;
  int G = dblk * 16;
  dot_kernel<<<dblk, 256, 0, stream>>>(h_t, h_p, lsrc, ldst, out, EL, G);
}